// Round 3
// baseline (137.402 us; speedup 1.0000x reference)
//
#include <hip/hip_runtime.h>
#include <math.h>

#define H 2048
#define W 2048
#define SEG 32
#define L (H / SEG)   // 64 rows per segment
#define BIG (1 << 20)
#define DCLAMP 2900   // > sqrt(2047^2+2048^2); caps f at 8.41e6 (exact in fp32)

// ---------------------------------------------------------------------------
// K0: zero the max scalar (avoid hipMemsetAsync inside capture).
// ---------------------------------------------------------------------------
__global__ void k0_init(unsigned int* __restrict__ maxp) { *maxp = 0u; }

// ---------------------------------------------------------------------------
// K1a: per (column j, segment s): local down-scan, BIG-encoded (v >= BIG means
// no background seen in segment yet; v-BIG = rows since segment top). Writes
// encoded down-dist ints into d_out (scratch). Per-segment summaries:
// A[s][j] = bottom-row down value, B[s][j] = top-row up value.
// ---------------------------------------------------------------------------
__global__ void k1a_local(const float* __restrict__ img, int* __restrict__ down,
                          int* __restrict__ A, int* __restrict__ B) {
    int j = blockIdx.x * blockDim.x + threadIdx.x;
    int s = blockIdx.y;
    int r0 = s * L;
    int d = BIG;
#pragma unroll 4
    for (int i = 0; i < L; ++i) {
        size_t idx = (size_t)(r0 + i) * W + j;
        bool z = img[idx] <= 0.5f;          // background
        d = z ? 0 : d + 1;
        down[idx] = d;
    }
    A[s * W + j] = d;
    int u = BIG;
#pragma unroll 4
    for (int i = L - 1; i >= 0; --i) {
        size_t idx = (size_t)(r0 + i) * W + j;
        bool z = img[idx] <= 0.5f;
        u = z ? 0 : u + 1;
    }
    B[s * W + j] = u;
}

// ---------------------------------------------------------------------------
// K1b: per column: resolve carries across segments IN PLACE.
// After: A[s][j] = resolved down-dist at row just above segment s,
//        B[s][j] = resolved up-dist at row just below segment s.
// ---------------------------------------------------------------------------
__global__ void k1b_carry(int* __restrict__ A, int* __restrict__ B) {
    int j = blockIdx.x * blockDim.x + threadIdx.x;
    int c = BIG;
    for (int s = 0; s < SEG; ++s) {
        int b = A[s * W + j];
        A[s * W + j] = c;
        c = (b < BIG) ? b : b - BIG + c;
    }
    c = BIG;
    for (int s = SEG - 1; s >= 0; --s) {
        int t = B[s * W + j];
        B[s * W + j] = c;
        c = (t < BIG) ? t : t - BIG + c;
    }
}

// ---------------------------------------------------------------------------
// K1c: per (column, segment), bottom-to-top: combine fixed-up down distance
// with running up distance; overwrite d_out in place with f = mask? d1*d1 : 0.
// dd clamped to [0, DCLAMP] so no garbage can reach k2.
// ---------------------------------------------------------------------------
__global__ void k1c_fix(const float* __restrict__ img, int* __restrict__ downf,
                        const int* __restrict__ A, const int* __restrict__ B) {
    int j = blockIdx.x * blockDim.x + threadIdx.x;
    int s = blockIdx.y;
    int r0 = s * L;
    int dc = A[s * W + j];
    int u  = B[s * W + j];
#pragma unroll 4
    for (int i = L - 1; i >= 0; --i) {
        size_t idx = (size_t)(r0 + i) * W + j;
        bool z = img[idx] <= 0.5f;
        u = z ? 0 : u + 1;
        int v = downf[idx];
        int dv = (v < BIG) ? v : v - BIG + dc;
        int dd = min(min(dv, u), DCLAMP);
        dd = max(dd, 0);
        float fd = (float)dd;
        ((float*)downf)[idx] = z ? 0.0f : fd * fd;
    }
}

// ---------------------------------------------------------------------------
// K2: exact row pass with early exit, one block per row through LDS.
// D[i,j] = min_{j'} f[i,j'] + (j-j')^2; candidates at offset d cost >= d^2 so
// stopping at d*d >= best is exact. In-place on d_out (block owns its row).
// Loop additionally hard-bounded at d <= 2048 (cannot hang).
// ---------------------------------------------------------------------------
__global__ void k2_row(float* __restrict__ buf, unsigned int* __restrict__ maxp) {
    __shared__ float srow[W];
    __shared__ float smax[4];
    int i = blockIdx.x;
    float* row = buf + (size_t)i * W;
#pragma unroll
    for (int k = 0; k < W / 256; ++k)
        srow[threadIdx.x + 256 * k] = row[threadIdx.x + 256 * k];
    __syncthreads();
    float lmax = 0.0f;
    float res[W / 256];
#pragma unroll
    for (int k = 0; k < W / 256; ++k) {
        int j = threadIdx.x + 256 * k;
        float best = srow[j];
        for (int d = 1; d <= 2048 && (float)(d * d) < best; ++d) {
            float q = (float)(d * d);
            int jm = j - d, jp = j + d;
            if (jm >= 0) best = fminf(best, srow[jm] + q);
            if (jp < W)  best = fminf(best, srow[jp] + q);
        }
        float r = sqrtf(best);
        res[k] = r;
        lmax = fmaxf(lmax, r);
    }
#pragma unroll
    for (int k = 0; k < W / 256; ++k)
        row[threadIdx.x + 256 * k] = res[k];
    // block max -> one atomic
    for (int o = 32; o > 0; o >>= 1) lmax = fmaxf(lmax, __shfl_down(lmax, o, 64));
    int lane = threadIdx.x & 63, wid = threadIdx.x >> 6;
    if (lane == 0) smax[wid] = lmax;
    __syncthreads();
    if (threadIdx.x == 0) {
        float mm = fmaxf(fmaxf(smax[0], smax[1]), fmaxf(smax[2], smax[3]));
        atomicMax(maxp, __float_as_uint(mm));  // valid: all values >= 0
    }
}

// ---------------------------------------------------------------------------
// K3: normalize in place and store as INT32 (reference output dtype is uint8,
// an integer dtype -> harness reads d_out as int32). Mirror numpy op order:
// v = d / m * 255 in fp32, then truncate toward zero.
// ---------------------------------------------------------------------------
__global__ void k3_norm(float* __restrict__ dist, const unsigned int* __restrict__ maxp) {
    size_t idx = (size_t)blockIdx.x * blockDim.x + threadIdx.x;
    float m = __uint_as_float(*maxp);
    float d = dist[idx];
    float v = (m > 0.0f) ? (d / m * 255.0f) : d;
    v = fminf(fmaxf(v, 0.0f), 255.0f);
    ((int*)dist)[idx] = (int)v;   // trunc toward zero, like astype(np.uint8)
}

extern "C" void kernel_launch(void* const* d_in, const int* in_sizes, int n_in,
                              void* d_out, int out_size, void* d_ws, size_t ws_size,
                              hipStream_t stream) {
    const float* img = (const float*)d_in[0];
    float* out = (float*)d_out;

    // ws layout: A (256KB) | B (256KB) | maxp (4B)
    char* ws = (char*)d_ws;
    int* A = (int*)ws;
    int* B = A + SEG * W;
    unsigned int* maxp = (unsigned int*)(B + SEG * W);

    int* down = (int*)out;  // d_out doubles as scratch: down ints, then f floats

    dim3 blk(256);
    k0_init<<<dim3(1), dim3(1), 0, stream>>>(maxp);
    k1a_local<<<dim3(W / 256, SEG), blk, 0, stream>>>(img, down, A, B);
    k1b_carry<<<dim3(W / 256), blk, 0, stream>>>(A, B);
    k1c_fix<<<dim3(W / 256, SEG), blk, 0, stream>>>(img, down, A, B);
    k2_row<<<dim3(H), blk, 0, stream>>>(out, maxp);
    k3_norm<<<dim3((H * W) / 256), blk, 0, stream>>>(out, maxp);
}